// Round 2
// baseline (1113.927 us; speedup 1.0000x reference)
//
#include <hip/hip_runtime.h>
#include <hip/hip_bf16.h>

// SwinBlock: fp32 in/out, bf16 MFMA GEMMs (64x64 tile) + fused windowed attention.
// B=32 H=W=56 C=256 NH=8 HD=32 WS=7 SS=3 L=49 nWin=64 -> N=2048 windows, M=100352 rows.

typedef unsigned short ushort_t;
typedef short bf16x8 __attribute__((ext_vector_type(8)));
typedef float f32x4 __attribute__((ext_vector_type(4)));

__device__ __forceinline__ float bf2f(unsigned short u) {
    union { unsigned int i; float f; } x; x.i = ((unsigned int)u) << 16; return x.f;
}
__device__ __forceinline__ unsigned short f2bf(float f) {
    union { float f; unsigned int i; } x; x.f = f;
    unsigned int r = x.i + 0x7fffu + ((x.i >> 16) & 1u);   // RNE
    return (unsigned short)(r >> 16);
}
__device__ __forceinline__ bf16x8 pack8(float4 a, float4 b) {
    bf16x8 r;
    r[0] = (short)f2bf(a.x); r[1] = (short)f2bf(a.y);
    r[2] = (short)f2bf(a.z); r[3] = (short)f2bf(a.w);
    r[4] = (short)f2bf(b.x); r[5] = (short)f2bf(b.y);
    r[6] = (short)f2bf(b.z); r[7] = (short)f2bf(b.w);
    return r;
}

// row m of the windowed/shifted activation -> element offset into x[B,H,W,C]
__device__ __forceinline__ long swin_src_off(int m) {
    int n = m / 49, l = m - n * 49;
    int b = n >> 6, win = n & 63;
    int wh = win >> 3, ww = win & 7;
    int i = l / 7, j = l - i * 7;
    int hs = wh * 7 + i + 3; if (hs >= 56) hs -= 56;   // roll(-3)
    int ws = ww * 7 + j + 3; if (ws >= 56) ws -= 56;
    return ((long)(b * 56 + hs) * 56 + ws) * 256;
}

// ---------------- GEMM: C[M,N] = act(A[M,K] * B + bias), C bf16 ----------------
// ABF: 1 = A is bf16 (intermediate), 0 = A is fp32 (model input)
// BLAYOUT 0: B fp32 [N,K] (out = A * W^T) ; 1: B fp32 [K,N]
// ACT 1: exact GELU.  AMAP 1: A rows gathered via swin_src_off (K==256, fp32 A).
template<int ABF, int BLAYOUT, int ACT, int AMAP>
__global__ __launch_bounds__(256)
void gemm64(const void* __restrict__ Av, const float* __restrict__ Bm,
            const float* __restrict__ bias, ushort_t* __restrict__ C,
            int M, int N, int K)
{
    __shared__ ushort_t As[64][40];   // +8 pad
    __shared__ ushort_t Bs[64][40];   // stored [n][k]
    const int tid = threadIdx.x;
    const int lane = tid & 63, wave = tid >> 6;
    const int row0 = blockIdx.x * 64, col0 = blockIdx.y * 64;
    const int wm = (wave >> 1) * 32, wn = (wave & 1) * 32;

    f32x4 acc[2][2] = {};

    const int ak = (tid & 3) * 8;                 // k offset within tile
    const int arow = row0 + (tid >> 2);
    long aoff;
    if (AMAP == 1) aoff = swin_src_off(arow) + ak;
    else           aoff = (long)arow * K + ak;

    long boff;
    if (BLAYOUT == 0) boff = (long)(col0 + (tid >> 2)) * K + ak;
    else              boff = (long)(tid >> 3) * N + col0 + (tid & 7) * 8;

    for (int k0 = 0; k0 < K; k0 += 32) {
        bf16x8 av, bv;
        if (ABF) {
            av = *(const bf16x8*)((const ushort_t*)Av + aoff + k0);
        } else {
            const float* ap = (const float*)Av + aoff + k0;
            av = pack8(*(const float4*)ap, *(const float4*)(ap + 4));
        }
        {
            const float* bp = Bm + boff + (BLAYOUT == 0 ? (long)k0 : (long)k0 * N);
            bv = pack8(*(const float4*)bp, *(const float4*)(bp + 4));
        }
        __syncthreads();                          // previous tile fully consumed
        *(bf16x8*)&As[tid >> 2][ak] = av;
        if (BLAYOUT == 0) {
            *(bf16x8*)&Bs[tid >> 2][ak] = bv;
        } else {
            const int kk = tid >> 3, n0 = (tid & 7) * 8;
            #pragma unroll
            for (int t = 0; t < 8; t++) Bs[n0 + t][kk] = (ushort_t)bv[t];
        }
        __syncthreads();
        #pragma unroll
        for (int mi = 0; mi < 2; mi++) {
            bf16x8 af = *(const bf16x8*)&As[wm + mi * 16 + (lane & 15)][(lane >> 4) * 8];
            #pragma unroll
            for (int ni = 0; ni < 2; ni++) {
                bf16x8 bfv = *(const bf16x8*)&Bs[wn + ni * 16 + (lane & 15)][(lane >> 4) * 8];
                acc[mi][ni] = __builtin_amdgcn_mfma_f32_16x16x32_bf16(af, bfv, acc[mi][ni], 0, 0, 0);
            }
        }
    }
    #pragma unroll
    for (int mi = 0; mi < 2; mi++) {
        #pragma unroll
        for (int ni = 0; ni < 2; ni++) {
            const int c = col0 + wn + ni * 16 + (lane & 15);
            const float bvv = bias[c];
            #pragma unroll
            for (int r = 0; r < 4; r++) {
                const int rr = row0 + wm + mi * 16 + (lane >> 4) * 4 + r;
                float v = acc[mi][ni][r] + bvv;
                if (ACT == 1) v = 0.5f * v * (1.0f + erff(v * 0.70710678118654752f));
                C[(long)rr * N + c] = f2bf(v);
            }
        }
    }
}

// ---------------- attention: one block per (window n, head h) ----------------
__global__ __launch_bounds__(256)
void attn_kernel(const ushort_t* __restrict__ qkv, const float* __restrict__ rpb,
                 ushort_t* __restrict__ out)
{
    __shared__ float q_s[49][36];
    __shared__ float k_s[49][36];
    __shared__ float v_t[32][52];   // transposed V
    __shared__ float S[49][52];
    __shared__ int   reg_s[49];

    const int blk = blockIdx.x;
    const int n = blk >> 3, h = blk & 7;
    const int tid = threadIdx.x;
    const int lane = tid & 63, wave = tid >> 6;
    const float scale = 0.17677669529663687f;    // 32^-0.5

    const long base = (long)n * 49 * 768 + h * 32;
    for (int e = tid; e < 49 * 32; e += 256) {
        int l = e >> 5, d = e & 31;
        long o = base + (long)l * 768 + d;
        q_s[l][d] = bf2f(qkv[o]) * scale;
        k_s[l][d] = bf2f(qkv[o + 256]);
        v_t[d][l] = bf2f(qkv[o + 512]);
    }
    if (tid < 49) {  // shifted-window mask region labels
        int win = n & 63, wh = win >> 3, ww = win & 7;
        int i = tid / 7, j = tid - (tid / 7) * 7;
        int hs = wh * 7 + i, wsx = ww * 7 + j;
        int rh = hs < 49 ? 0 : (hs < 53 ? 1 : 2);
        int rw = wsx < 49 ? 0 : (wsx < 53 ? 1 : 2);
        reg_s[tid] = rh * 3 + rw;
    }
    __syncthreads();

    // S = q k^T + rel-pos bias + mask
    for (int e = tid; e < 49 * 49; e += 256) {
        int i = e / 49, j = e - i * 49;
        const float4* qp = (const float4*)q_s[i];
        const float4* kp = (const float4*)k_s[j];
        float s = 0.f;
        #pragma unroll
        for (int kk = 0; kk < 8; kk++) {
            float4 a = qp[kk], b = kp[kk];
            s += a.x * b.x + a.y * b.y + a.z * b.z + a.w * b.w;
        }
        int yi = i / 7, xi = i - yi * 7, yj = j / 7, xj = j - yj * 7;
        int ridx = (yi - yj + 6) * 13 + (xi - xj + 6);
        s += rpb[ridx * 8 + h];
        if (reg_s[i] != reg_s[j]) s -= 100.f;
        S[i][j] = s;
    }
    __syncthreads();

    // row softmax (one wave per row)
    for (int r = wave; r < 49; r += 4) {
        float v = (lane < 49) ? S[r][lane] : -1e30f;
        float mx = v;
        #pragma unroll
        for (int off = 32; off; off >>= 1) mx = fmaxf(mx, __shfl_xor(mx, off));
        float pv = (lane < 49) ? __expf(v - mx) : 0.f;
        float sum = pv;
        #pragma unroll
        for (int off = 32; off; off >>= 1) sum += __shfl_xor(sum, off);
        if (lane < 49) S[r][lane] = pv / sum;
    }
    __syncthreads();

    // out = P V
    for (int e = tid; e < 49 * 32; e += 256) {
        int i = e >> 5, d = e & 31;
        const float4* pp = (const float4*)S[i];
        const float4* vp = (const float4*)v_t[d];
        float acc = 0.f;
        #pragma unroll
        for (int jj = 0; jj < 12; jj++) {
            float4 p4 = pp[jj], v4 = vp[jj];
            acc += p4.x * v4.x + p4.y * v4.y + p4.z * v4.z + p4.w * v4.w;
        }
        acc += S[i][48] * v_t[d][48];
        out[((long)n * 49 + i) * 256 + h * 32 + d] = f2bf(acc);
    }
}

// ---------------- LN1: x1 = x + LN(reverse_window(proj)) ----------------
__global__ __launch_bounds__(256)
void ln1_kernel(const ushort_t* __restrict__ proj, const float* __restrict__ x,
                const float* __restrict__ gamma, const float* __restrict__ beta,
                float* __restrict__ x1f, ushort_t* __restrict__ x1b)
{
    const int wave = threadIdx.x >> 6, lane = threadIdx.x & 63;
    const int p = blockIdx.x * 4 + wave;
    const int b = p / 3136, rem = p - b * 3136;
    const int hh = rem / 56, wc = rem - hh * 56;
    int hs = hh + 53; if (hs >= 56) hs -= 56;    // roll(+3) reverse
    int ws = wc + 53; if (ws >= 56) ws -= 56;
    const int wh = hs / 7, ii = hs - wh * 7;
    const int wwi = ws / 7, jj = ws - wwi * 7;
    const long srow = (long)(b * 64 + wh * 8 + wwi) * 49 + ii * 7 + jj;
    const int c = lane * 4;

    ushort4 av = *(const ushort4*)(proj + srow * 256 + c);
    float a0 = bf2f(av.x), a1 = bf2f(av.y), a2 = bf2f(av.z), a3 = bf2f(av.w);
    float s = a0 + a1 + a2 + a3;
    float ss = a0 * a0 + a1 * a1 + a2 * a2 + a3 * a3;
    #pragma unroll
    for (int off = 32; off; off >>= 1) { s += __shfl_xor(s, off); ss += __shfl_xor(ss, off); }
    const float mu = s * (1.0f / 256.0f);
    const float rstd = rsqrtf(ss * (1.0f / 256.0f) - mu * mu + 1e-5f);

    float4 gv = *(const float4*)(gamma + c);
    float4 bev = *(const float4*)(beta + c);
    float4 xv = *(const float4*)(x + (long)p * 256 + c);
    float o0 = xv.x + (a0 - mu) * rstd * gv.x + bev.x;
    float o1 = xv.y + (a1 - mu) * rstd * gv.y + bev.y;
    float o2 = xv.z + (a2 - mu) * rstd * gv.z + bev.z;
    float o3 = xv.w + (a3 - mu) * rstd * gv.w + bev.w;
    *(float4*)(x1f + (long)p * 256 + c) = make_float4(o0, o1, o2, o3);
    ushort4 ob; ob.x = f2bf(o0); ob.y = f2bf(o1); ob.z = f2bf(o2); ob.w = f2bf(o3);
    *(ushort4*)(x1b + (long)p * 256 + c) = ob;
}

// ---------------- LN2: out = x1 + LN(m), fp32 out ----------------
__global__ __launch_bounds__(256)
void ln2_kernel(const ushort_t* __restrict__ m, const float* __restrict__ x1f,
                const float* __restrict__ gamma, const float* __restrict__ beta,
                float* __restrict__ out)
{
    const int wave = threadIdx.x >> 6, lane = threadIdx.x & 63;
    const int p = blockIdx.x * 4 + wave;
    const int c = lane * 4;

    ushort4 av = *(const ushort4*)(m + (long)p * 256 + c);
    float a0 = bf2f(av.x), a1 = bf2f(av.y), a2 = bf2f(av.z), a3 = bf2f(av.w);
    float s = a0 + a1 + a2 + a3;
    float ss = a0 * a0 + a1 * a1 + a2 * a2 + a3 * a3;
    #pragma unroll
    for (int off = 32; off; off >>= 1) { s += __shfl_xor(s, off); ss += __shfl_xor(ss, off); }
    const float mu = s * (1.0f / 256.0f);
    const float rstd = rsqrtf(ss * (1.0f / 256.0f) - mu * mu + 1e-5f);

    float4 gv = *(const float4*)(gamma + c);
    float4 bev = *(const float4*)(beta + c);
    float4 xv = *(const float4*)(x1f + (long)p * 256 + c);
    float4 ov;
    ov.x = xv.x + (a0 - mu) * rstd * gv.x + bev.x;
    ov.y = xv.y + (a1 - mu) * rstd * gv.y + bev.y;
    ov.z = xv.z + (a2 - mu) * rstd * gv.z + bev.z;
    ov.w = xv.w + (a3 - mu) * rstd * gv.w + bev.w;
    *(float4*)(out + (long)p * 256 + c) = ov;
}

extern "C" void kernel_launch(void* const* d_in, const int* in_sizes, int n_in,
                              void* d_out, int out_size, void* d_ws, size_t ws_size,
                              hipStream_t stream) {
    const float* x      = (const float*)d_in[0];
    const float* qkv_w  = (const float*)d_in[1];
    const float* qkv_b  = (const float*)d_in[2];
    const float* proj_w = (const float*)d_in[3];
    const float* proj_b = (const float*)d_in[4];
    const float* rpb    = (const float*)d_in[5];
    const float* gamma1 = (const float*)d_in[6];
    const float* beta1  = (const float*)d_in[7];
    const float* w1     = (const float*)d_in[8];
    const float* b1     = (const float*)d_in[9];
    const float* w2     = (const float*)d_in[10];
    const float* b2     = (const float*)d_in[11];
    const float* gamma2 = (const float*)d_in[12];
    const float* beta2  = (const float*)d_in[13];
    float* outf = (float*)d_out;

    // d_out (102,760,448 B fp32) doubles as bf16 scratch until the final write:
    char* ob = (char*)d_out;
    ushort_t* attnout = (ushort_t*)ob;                    // [0, 51.4MB)   step2->3
    ushort_t* projb   = (ushort_t*)(ob + 51380224ULL);    // [51.4, 102.8) step3->4
    ushort_t* x1b     = (ushort_t*)ob;                    // [0, 51.4MB)   step4->5 (attnout dead)

    char* ws = (char*)d_ws;
    ushort_t* qkvb = (ushort_t*)ws;                       // 154.1MB, steps 1->2
    float*    x1f  = (float*)ws;                          // 102.8MB, step 4->7 (qkv dead)
    ushort_t* hbuf = (ushort_t*)(ws + 102760448ULL);      // 102.8MB (half-M hidden)
    ushort_t* mbuf = (ushort_t*)(ws + 205520896ULL);      // 51.4MB  -> peak ws 256.9MB

    const int M = 100352, Mh = 50176;
    dim3 blk(256);
    // 1. QKV GEMM with fused roll+window gather on A rows (fp32 A, fp32 W[768,256])
    gemm64<0, 0, 0, 1><<<dim3(M / 64, 12), blk, 0, stream>>>(x, qkv_w, qkv_b, qkvb, M, 768, 256);
    // 2. windowed attention (bias + shift mask + softmax + PV)
    attn_kernel<<<dim3(16384), blk, 0, stream>>>(qkvb, rpb, attnout);
    // 3. output projection (bf16 A, fp32 W[256,256])
    gemm64<1, 0, 0, 0><<<dim3(M / 64, 4), blk, 0, stream>>>(attnout, proj_w, proj_b, projb, M, 256, 256);
    // 4. x1 = x + LN(reverse(proj))
    ln1_kernel<<<dim3(M / 4), blk, 0, stream>>>(projb, x, gamma1, beta1, x1f, x1b);
    // 5/6. MLP in two M-halves: h = gelu(x1 @ w1 + b1); m = h @ w2 + b2
    for (int half = 0; half < 2; half++) {
        gemm64<1, 1, 1, 0><<<dim3(Mh / 64, 16), blk, 0, stream>>>(
            x1b + (long)half * Mh * 256, w1, b1, hbuf, Mh, 1024, 256);
        gemm64<1, 1, 0, 0><<<dim3(Mh / 64, 4), blk, 0, stream>>>(
            hbuf, w2, b2, mbuf + (long)half * Mh * 256, Mh, 256, 1024);
    }
    // 7. out = x1 + LN(m)  (fp32 final write over all of d_out)
    ln2_kernel<<<dim3(M / 4), blk, 0, stream>>>(mbuf, x1f, gamma2, beta2, outf);
}

// Round 3
// 602.665 us; speedup vs baseline: 1.8483x; 1.8483x over previous
//
#include <hip/hip_runtime.h>
#include <hip/hip_bf16.h>

// SwinBlock r3: m97-style 128^2 global_load_lds GEMMs + MFMA windowed attention.
// B=32 H=W=56 C=256 NH=8 HD=32 WS=7 SS=3 L=49 nWin=64 -> 2048 windows, M=100352 rows.

typedef unsigned short ushort_t;
typedef short bf16x8 __attribute__((ext_vector_type(8)));
typedef float f32x4 __attribute__((ext_vector_type(4)));

__device__ __forceinline__ float bf2f(unsigned short u) {
    union { unsigned int i; float f; } x; x.i = ((unsigned int)u) << 16; return x.f;
}
__device__ __forceinline__ unsigned short f2bf(float f) {
    union { float f; unsigned int i; } x; x.f = f;
    unsigned int r = x.i + 0x7fffu + ((x.i >> 16) & 1u);   // RNE
    return (unsigned short)(r >> 16);
}
__device__ __forceinline__ bf16x8 pack8(float4 a, float4 b) {
    bf16x8 r;
    r[0] = (short)f2bf(a.x); r[1] = (short)f2bf(a.y);
    r[2] = (short)f2bf(a.z); r[3] = (short)f2bf(a.w);
    r[4] = (short)f2bf(b.x); r[5] = (short)f2bf(b.y);
    r[6] = (short)f2bf(b.z); r[7] = (short)f2bf(b.w);
    return r;
}
__device__ __forceinline__ void gl_lds16(const ushort_t* g, ushort_t* l) {
    __builtin_amdgcn_global_load_lds((const __attribute__((address_space(1))) void*)g,
                                     (__attribute__((address_space(3))) void*)l, 16, 0, 0);
}

// row m of the windowed/shifted activation -> element offset into x[B,H,W,C]
__device__ __forceinline__ long swin_src_off(int m) {
    int n = m / 49, l = m - n * 49;
    int b = n >> 6, win = n & 63;
    int wh = win >> 3, ww = win & 7;
    int i = l / 7, j = l - i * 7;
    int hs = wh * 7 + i + 3; if (hs >= 56) hs -= 56;   // roll(-3)
    int ws = ww * 7 + j + 3; if (ws >= 56) ws -= 56;
    return ((long)(b * 56 + hs) * 56 + ws) * 256;
}

// ---------------- prep: gather+convert x -> xg bf16 [M][256] ----------------
__global__ __launch_bounds__(256)
void xgather(const float* __restrict__ x, ushort_t* __restrict__ xg)
{
    int t = blockIdx.x * 256 + threadIdx.x;   // M*32 threads, 8 elems each
    int row = t >> 5, ch = (t & 31) * 8;
    const float* src = x + swin_src_off(row) + ch;
    float4 a = *(const float4*)src, b = *(const float4*)(src + 4);
    *(bf16x8*)(xg + (long)row * 256 + ch) = pack8(a, b);
}

// ---------------- prep: weights fp32 -> bf16 [N][K] (optional transpose) ----
template<int SRCT>
__global__ __launch_bounds__(256)
void convW(const float* __restrict__ src, ushort_t* __restrict__ dst, int N, int kshift)
{
    int idx = blockIdx.x * 256 + threadIdx.x;
    int kk = idx & ((1 << kshift) - 1), nn = idx >> kshift;
    float v = SRCT ? src[(long)kk * N + nn] : src[idx];
    dst[idx] = f2bf(v);
}

// ---------------- GEMM 128x128, BK=32, global_load_lds staging ----------------
// A bf16 [M][K], W bf16 [N][K], C bf16 [M][N] = act(A*W^T + bias)
template<int ACT>
__global__ __launch_bounds__(256)
void gemm128(const ushort_t* __restrict__ A, const ushort_t* __restrict__ W,
             const float* __restrict__ bias, ushort_t* __restrict__ C,
             int M, int N, int K)
{
    __shared__ ushort_t As[128 * 32];
    __shared__ ushort_t Bs[128 * 32];
    const int t = threadIdx.x, lane = t & 63, wave = t >> 6;
    const int row0 = blockIdx.x * 128, col0 = blockIdx.y * 128;
    const int wm = (wave >> 1) * 64, wn = (wave & 1) * 64;

    const ushort_t* ag0 = A + (long)(row0 + (t >> 2)) * K + (t & 3) * 8;
    const ushort_t* ag1 = A + (long)(row0 + 64 + (t >> 2)) * K + (t & 3) * 8;
    const ushort_t* bg0 = W + (long)(col0 + (t >> 2)) * K + (t & 3) * 8;
    const ushort_t* bg1 = W + (long)(col0 + 64 + (t >> 2)) * K + (t & 3) * 8;
    ushort_t* la0 = &As[t * 8];        ushort_t* la1 = &As[2048 + t * 8];
    ushort_t* lb0 = &Bs[t * 8];        ushort_t* lb1 = &Bs[2048 + t * 8];

    f32x4 acc[4][4] = {};
    for (int k0 = 0; k0 < K; k0 += 32) {
        __syncthreads();                 // previous tile fully consumed
        gl_lds16(ag0 + k0, la0);
        gl_lds16(ag1 + k0, la1);
        gl_lds16(bg0 + k0, lb0);
        gl_lds16(bg1 + k0, lb1);
        __syncthreads();                 // vmcnt(0) drain -> data resident
        bf16x8 af[4], bw[4];
        #pragma unroll
        for (int i = 0; i < 4; i++) {
            af[i] = *(const bf16x8*)&As[(wm + i * 16 + (lane & 15)) * 32 + (lane >> 4) * 8];
            bw[i] = *(const bf16x8*)&Bs[(wn + i * 16 + (lane & 15)) * 32 + (lane >> 4) * 8];
        }
        #pragma unroll
        for (int mi = 0; mi < 4; mi++)
            #pragma unroll
            for (int ni = 0; ni < 4; ni++)
                acc[mi][ni] = __builtin_amdgcn_mfma_f32_16x16x32_bf16(af[mi], bw[ni], acc[mi][ni], 0, 0, 0);
    }
    #pragma unroll
    for (int mi = 0; mi < 4; mi++)
        #pragma unroll
        for (int ni = 0; ni < 4; ni++) {
            const int c = col0 + wn + ni * 16 + (lane & 15);
            const float bv = bias[c];
            #pragma unroll
            for (int r = 0; r < 4; r++) {
                const int rr = row0 + wm + mi * 16 + (lane >> 4) * 4 + r;
                float v = acc[mi][ni][r] + bv;
                if (ACT) v = 0.5f * v * (1.0f + erff(v * 0.70710678118654752f));
                C[(long)rr * N + c] = f2bf(v);
            }
        }
}

// ---------------- MFMA attention: one wave per (window, head) ----------------
__global__ __launch_bounds__(64)
void attn_mfma(const ushort_t* __restrict__ qkv, const float* __restrict__ rpb,
               ushort_t* __restrict__ out)
{
    __shared__ ushort_t v_t[32 * 72];    // V^T [d][j], pad 72
    __shared__ ushort_t p_lds[64 * 72];  // P   [i][j], pad 72
    __shared__ float bias_s[169];

    const int blk = blockIdx.x;
    const int n = blk >> 3, h = blk & 7;
    const int l = threadIdx.x;           // 0..63
    const long wbase = (long)n * 49 * 768 + h * 32;
    const float scale = 0.17677669529663687f;   // 32^-0.5

    // stage V^T (rows >=49 clamped to row 48 -> finite padding)
    {
        int j = min(l, 48);
        const ushort_t* vr = qkv + wbase + (long)j * 768 + 512;
        #pragma unroll
        for (int c = 0; c < 4; c++) {
            bf16x8 vv = *(const bf16x8*)(vr + c * 8);
            #pragma unroll
            for (int e = 0; e < 8; e++) v_t[(c * 8 + e) * 72 + l] = (ushort_t)vv[e];
        }
    }
    for (int idx = l; idx < 169; idx += 64) bias_s[idx] = rpb[idx * 8 + h];
    __syncthreads();

    // QK^T: A=Q frag (row=l&15, k=d), B=K frag (col=l&15, k=d), direct from global
    f32x4 s[4][4] = {};
    {
        bf16x8 aq[4], bk[4];
        #pragma unroll
        for (int mt = 0; mt < 4; mt++) {
            int i = min(mt * 16 + (l & 15), 48);
            aq[mt] = *(const bf16x8*)(qkv + wbase + (long)i * 768 + (l >> 4) * 8);
        }
        #pragma unroll
        for (int nt = 0; nt < 4; nt++) {
            int j = min(nt * 16 + (l & 15), 48);
            bk[nt] = *(const bf16x8*)(qkv + wbase + (long)j * 768 + 256 + (l >> 4) * 8);
        }
        #pragma unroll
        for (int mt = 0; mt < 4; mt++)
            #pragma unroll
            for (int nt = 0; nt < 4; nt++)
                s[mt][nt] = __builtin_amdgcn_mfma_f32_16x16x32_bf16(aq[mt], bk[nt], s[mt][nt], 0, 0, 0);
    }

    // in-register softmax (row i lives in one 16-lane group), P bf16 unnormalized
    const int win = n & 63, wh = win >> 3, ww = win & 7;
    int yj[4], xj[4], regj[4]; bool jv[4];
    #pragma unroll
    for (int nt = 0; nt < 4; nt++) {
        int j = nt * 16 + (l & 15);
        jv[nt] = (j <= 48);
        int jc = min(j, 48);
        yj[nt] = jc / 7; xj[nt] = jc - yj[nt] * 7;
        int hs = wh * 7 + yj[nt], wsx = ww * 7 + xj[nt];
        regj[nt] = (hs < 49 ? 0 : (hs < 53 ? 1 : 2)) * 3 + (wsx < 49 ? 0 : (wsx < 53 ? 1 : 2));
    }
    float rinv[4][4];
    #pragma unroll
    for (int mt = 0; mt < 4; mt++) {
        #pragma unroll
        for (int r = 0; r < 4; r++) {
            int i = mt * 16 + (l >> 4) * 4 + r;
            int ic = min(i, 48);
            int yi = ic / 7, xi = ic - yi * 7;
            int hs = wh * 7 + yi, wsx = ww * 7 + xi;
            int regi = (hs < 49 ? 0 : (hs < 53 ? 1 : 2)) * 3 + (wsx < 49 ? 0 : (wsx < 53 ? 1 : 2));
            float val[4];
            #pragma unroll
            for (int nt = 0; nt < 4; nt++) {
                float v = s[mt][nt][r] * scale + bias_s[(yi - yj[nt] + 6) * 13 + (xi - xj[nt] + 6)];
                if (regi != regj[nt]) v -= 100.f;
                val[nt] = jv[nt] ? v : -1e30f;
            }
            float mx = fmaxf(fmaxf(val[0], val[1]), fmaxf(val[2], val[3]));
            #pragma unroll
            for (int off = 1; off <= 8; off <<= 1) mx = fmaxf(mx, __shfl_xor(mx, off));
            float sum = 0.f;
            #pragma unroll
            for (int nt = 0; nt < 4; nt++) { val[nt] = __expf(val[nt] - mx); sum += val[nt]; }
            #pragma unroll
            for (int off = 1; off <= 8; off <<= 1) sum += __shfl_xor(sum, off);
            rinv[mt][r] = 1.0f / sum;
            #pragma unroll
            for (int nt = 0; nt < 4; nt++)
                p_lds[i * 72 + nt * 16 + (l & 15)] = f2bf(val[nt]);
        }
    }
    __syncthreads();

    // PV: A=P frag from p_lds, B=V frag from v_t; K=64 in 2 steps
    f32x4 o[4][2] = {};
    #pragma unroll
    for (int ks = 0; ks < 2; ks++) {
        bf16x8 pa[4], vb[2];
        #pragma unroll
        for (int mt = 0; mt < 4; mt++)
            pa[mt] = *(const bf16x8*)&p_lds[(mt * 16 + (l & 15)) * 72 + ks * 32 + (l >> 4) * 8];
        #pragma unroll
        for (int nt = 0; nt < 2; nt++)
            vb[nt] = *(const bf16x8*)&v_t[(nt * 16 + (l & 15)) * 72 + ks * 32 + (l >> 4) * 8];
        #pragma unroll
        for (int mt = 0; mt < 4; mt++)
            #pragma unroll
            for (int nt = 0; nt < 2; nt++)
                o[mt][nt] = __builtin_amdgcn_mfma_f32_16x16x32_bf16(pa[mt], vb[nt], o[mt][nt], 0, 0, 0);
    }
    #pragma unroll
    for (int mt = 0; mt < 4; mt++)
        #pragma unroll
        for (int r = 0; r < 4; r++) {
            int i = mt * 16 + (l >> 4) * 4 + r;
            if (i < 49) {
                float rs = rinv[mt][r];
                #pragma unroll
                for (int nt = 0; nt < 2; nt++) {
                    int d = nt * 16 + (l & 15);
                    out[((long)n * 49 + i) * 256 + h * 32 + d] = f2bf(o[mt][nt][r] * rs);
                }
            }
        }
}

// ---------------- LN1: x1 = x + LN(reverse_window(proj)) ----------------
__global__ __launch_bounds__(256)
void ln1_kernel(const ushort_t* __restrict__ proj, const float* __restrict__ x,
                const float* __restrict__ gamma, const float* __restrict__ beta,
                float* __restrict__ x1f, ushort_t* __restrict__ x1b)
{
    const int wave = threadIdx.x >> 6, lane = threadIdx.x & 63;
    const int p = blockIdx.x * 4 + wave;
    const int b = p / 3136, rem = p - b * 3136;
    const int hh = rem / 56, wc = rem - hh * 56;
    int hs = hh + 53; if (hs >= 56) hs -= 56;    // roll(+3) reverse
    int ws = wc + 53; if (ws >= 56) ws -= 56;
    const int wh = hs / 7, ii = hs - wh * 7;
    const int wwi = ws / 7, jj = ws - wwi * 7;
    const long srow = (long)(b * 64 + wh * 8 + wwi) * 49 + ii * 7 + jj;
    const int c = lane * 4;

    ushort4 av = *(const ushort4*)(proj + srow * 256 + c);
    float a0 = bf2f(av.x), a1 = bf2f(av.y), a2 = bf2f(av.z), a3 = bf2f(av.w);
    float s = a0 + a1 + a2 + a3;
    float ss = a0 * a0 + a1 * a1 + a2 * a2 + a3 * a3;
    #pragma unroll
    for (int off = 32; off; off >>= 1) { s += __shfl_xor(s, off); ss += __shfl_xor(ss, off); }
    const float mu = s * (1.0f / 256.0f);
    const float rstd = rsqrtf(ss * (1.0f / 256.0f) - mu * mu + 1e-5f);

    float4 gv = *(const float4*)(gamma + c);
    float4 bev = *(const float4*)(beta + c);
    float4 xv = *(const float4*)(x + (long)p * 256 + c);
    float o0 = xv.x + (a0 - mu) * rstd * gv.x + bev.x;
    float o1 = xv.y + (a1 - mu) * rstd * gv.y + bev.y;
    float o2 = xv.z + (a2 - mu) * rstd * gv.z + bev.z;
    float o3 = xv.w + (a3 - mu) * rstd * gv.w + bev.w;
    *(float4*)(x1f + (long)p * 256 + c) = make_float4(o0, o1, o2, o3);
    ushort4 ob; ob.x = f2bf(o0); ob.y = f2bf(o1); ob.z = f2bf(o2); ob.w = f2bf(o3);
    *(ushort4*)(x1b + (long)p * 256 + c) = ob;
}

// ---------------- LN2: out = x1 + LN(m), fp32 out ----------------
__global__ __launch_bounds__(256)
void ln2_kernel(const ushort_t* __restrict__ m, const float* __restrict__ x1f,
                const float* __restrict__ gamma, const float* __restrict__ beta,
                float* __restrict__ out)
{
    const int wave = threadIdx.x >> 6, lane = threadIdx.x & 63;
    const int p = blockIdx.x * 4 + wave;
    const int c = lane * 4;

    ushort4 av = *(const ushort4*)(m + (long)p * 256 + c);
    float a0 = bf2f(av.x), a1 = bf2f(av.y), a2 = bf2f(av.z), a3 = bf2f(av.w);
    float s = a0 + a1 + a2 + a3;
    float ss = a0 * a0 + a1 * a1 + a2 * a2 + a3 * a3;
    #pragma unroll
    for (int off = 32; off; off >>= 1) { s += __shfl_xor(s, off); ss += __shfl_xor(ss, off); }
    const float mu = s * (1.0f / 256.0f);
    const float rstd = rsqrtf(ss * (1.0f / 256.0f) - mu * mu + 1e-5f);

    float4 gv = *(const float4*)(gamma + c);
    float4 bev = *(const float4*)(beta + c);
    float4 xv = *(const float4*)(x1f + (long)p * 256 + c);
    float4 ov;
    ov.x = xv.x + (a0 - mu) * rstd * gv.x + bev.x;
    ov.y = xv.y + (a1 - mu) * rstd * gv.y + bev.y;
    ov.z = xv.z + (a2 - mu) * rstd * gv.z + bev.z;
    ov.w = xv.w + (a3 - mu) * rstd * gv.w + bev.w;
    *(float4*)(out + (long)p * 256 + c) = ov;
}

extern "C" void kernel_launch(void* const* d_in, const int* in_sizes, int n_in,
                              void* d_out, int out_size, void* d_ws, size_t ws_size,
                              hipStream_t stream) {
    const float* x      = (const float*)d_in[0];
    const float* qkv_w  = (const float*)d_in[1];
    const float* qkv_b  = (const float*)d_in[2];
    const float* proj_w = (const float*)d_in[3];
    const float* proj_b = (const float*)d_in[4];
    const float* rpb    = (const float*)d_in[5];
    const float* gamma1 = (const float*)d_in[6];
    const float* beta1  = (const float*)d_in[7];
    const float* w1     = (const float*)d_in[8];
    const float* b1     = (const float*)d_in[9];
    const float* w2     = (const float*)d_in[10];
    const float* b2     = (const float*)d_in[11];
    const float* gamma2 = (const float*)d_in[12];
    const float* beta2  = (const float*)d_in[13];
    float* outf = (float*)d_out;

    // d_out (102,760,448 B) as scratch until the final fp32 write:
    char* ob = (char*)d_out;
    ushort_t* xg      = (ushort_t*)ob;                    // [0,51.4M)   prep -> G1
    ushort_t* attnout = (ushort_t*)(ob + 51380224ULL);    // [51.4,102.8) attn -> G2
    ushort_t* projb   = (ushort_t*)ob;                    // [0,51.4M)   G2 -> LN1 (xg dead)
    ushort_t* x1b     = (ushort_t*)(ob + 51380224ULL);    // [51.4,102.8) LN1 -> MLP (attnout dead)

    char* ws = (char*)d_ws;
    ushort_t* qkvb  = (ushort_t*)ws;                      // [0,154.1M)  G1 -> attn
    float*    x1f   = (float*)ws;                         // [0,102.8M)  LN1 -> LN2 (qkvb dead)
    ushort_t* hbuf  = (ushort_t*)(ws + 102760448ULL);     // [102.8,154.1M) per MLP chunk
    ushort_t* mbuf  = (ushort_t*)(ws + 154140672ULL);     // [154.1,205.5M)
    ushort_t* wqkvb = (ushort_t*)(ws + 205520896ULL);     // bf16 weights [N][K]
    ushort_t* wprojb= (ushort_t*)(ws + 205520896ULL + 393216ULL);
    ushort_t* w1t   = (ushort_t*)(ws + 205520896ULL + 524288ULL);
    ushort_t* w2t   = (ushort_t*)(ws + 205520896ULL + 1048576ULL);

    const int M = 100352, MC = 25088;
    dim3 blk(256);
    // prep
    xgather<<<dim3(M / 8), blk, 0, stream>>>(x, xg);
    convW<0><<<dim3(768),  blk, 0, stream>>>(qkv_w,  wqkvb,  768,  8);   // [768][256]
    convW<0><<<dim3(256),  blk, 0, stream>>>(proj_w, wprojb, 256,  8);   // [256][256]
    convW<1><<<dim3(1024), blk, 0, stream>>>(w1,     w1t,    1024, 8);   // [256][1024] -> [1024][256]
    convW<1><<<dim3(1024), blk, 0, stream>>>(w2,     w2t,    256, 10);   // [1024][256] -> [256][1024]
    // 1. qkv = xg @ Wqkv^T + b
    gemm128<0><<<dim3(784, 6), blk, 0, stream>>>(xg, wqkvb, qkv_b, qkvb, M, 768, 256);
    // 2. windowed attention
    attn_mfma<<<dim3(16384), dim3(64), 0, stream>>>(qkvb, rpb, attnout);
    // 3. proj
    gemm128<0><<<dim3(784, 2), blk, 0, stream>>>(attnout, wprojb, proj_b, projb, M, 256, 256);
    // 4. x1 = x + LN(reverse(proj))
    ln1_kernel<<<dim3(M / 4), blk, 0, stream>>>(projb, x, gamma1, beta1, x1f, x1b);
    // 5/6. MLP in 4 M-chunks
    for (int c4 = 0; c4 < 4; c4++) {
        const ushort_t* xc = x1b + (long)c4 * MC * 256;
        gemm128<1><<<dim3(196, 8), blk, 0, stream>>>(xc, w1t, b1, hbuf, MC, 1024, 256);
        gemm128<0><<<dim3(196, 2), blk, 0, stream>>>(hbuf, w2t, b2, mbuf + (long)c4 * MC * 256, MC, 256, 1024);
    }
    // 7. out = x1 + LN(m)
    ln2_kernel<<<dim3(M / 4), blk, 0, stream>>>(mbuf, x1f, gamma2, beta2, outf);
}